// Round 19
// baseline (700.368 us; speedup 1.0000x reference)
//
#include <hip/hip_runtime.h>
#include <hip/hip_bf16.h>

#define T_  1024
#define B_  8
#define D_  1024
#define H_  16
#define DH_ 64
#define FF_ 4096
#define MROWS (T_*B_)   // 8192 token rows, row m = t*B + b

typedef __attribute__((ext_vector_type(8))) short short8;     // 8 bf16 MFMA operand
typedef __attribute__((ext_vector_type(4))) float f32x4;
typedef __attribute__((ext_vector_type(4))) unsigned short us4;
typedef __attribute__((ext_vector_type(4))) unsigned int  u32x4;

__device__ __forceinline__ unsigned short f2b(float f){
  unsigned int u = __builtin_bit_cast(unsigned int, f);
  u += 0x7FFFu + ((u >> 16) & 1u);          // RNE
  return (unsigned short)(u >> 16);
}
__device__ __forceinline__ float b2f(unsigned short h){
  unsigned int u = ((unsigned int)h) << 16;
  return __builtin_bit_cast(float, u);
}

__device__ __forceinline__ void glds16(const unsigned short* g, unsigned short* l){
  __builtin_amdgcn_global_load_lds(
    (const __attribute__((address_space(1))) unsigned int*)g,
    (__attribute__((address_space(3))) unsigned int*)l, 16, 0, 0);
}

enum { FRELU=1 };

// ================= gemm256<BN>: 256xBN tile, BK=32, 8 waves, 2-buffer multi-block =================
// m97-style: compute -> barrier -> stage(kt+2 into just-freed buf) -> counted vmcnt(S) for kt+1
// -> barrier. 2 buffers => <256> 64KB LDS = 2 blocks/CU, <128> 48KB = 3 blocks/CU; inter-block
// wave overlap fills the barrier/read stalls (m114/m97 mechanism).
// CRITICAL: launch_bounds min-waves MUST be 2 — (512,4) caps regs below the ~232 needed and
// spills acc to scratch (round-17: VGPR 64, 1.9GB scratch/dispatch, 4.7x slowdown).
// LDS swizzle: byte bits[5:4] ^= row bits[2:1] (conflict-free 2 lanes/bank).
// BN=256: wave grid 2x4, wave tile 128x64 (acc 8x4, 12 reads : 32 MFMA).
// BN=128: wave grid 4x2, wave tile  64x64 (acc 4x4,  8 reads : 16 MFMA).
// N-split option (N1): blocks with n0>=N1 use (A1b, Btb) — fuses two GEMMs into one launch.
template<int BN>
__global__ __launch_bounds__(512, 2) void gemm256(
    const unsigned short* __restrict__ A1, const unsigned short* __restrict__ A2,
    int K1, long lda,
    const unsigned short* __restrict__ Bt, long ldb,
    unsigned short* __restrict__ C, long ldc,
    const float* __restrict__ bias, int K, int flags,
    const unsigned short* __restrict__ A1b, const unsigned short* __restrict__ Btb,
    int N1)
{
  constexpr int BM = 256, BK = 32;
  constexpr int NBQ = BN/128;               // B-loads per thread per stage
  constexpr int S   = 2 + NBQ;              // total loads per thread per stage
  constexpr int NWC = (BN==256) ? 4 : 2;    // wave-cols (each 64 wide)
  constexpr int WMF = (BN==256) ? 8 : 4;    // m-frags per wave
  constexpr int BUFSZ = 16384 + BN*64;      // A 16KB + B
  extern __shared__ char L[];               // 2 x BUFSZ

  int t = threadIdx.x, w = t >> 6, l = t & 63;

  // T1: XCD-chunked swizzle (identity unless nwg%8==0; all our grids are %8)
  int nx = gridDim.x;
  int nwg = nx * gridDim.y;
  int lin = blockIdx.y*nx + blockIdx.x;
  if (!(nwg & 7)) lin = (lin & 7)*(nwg >> 3) + (lin >> 3);
  int bx = lin % nx, by = lin / nx;
  int m0 = by*BM, n0 = bx*BN;

  // N-split operand selection (block-uniform; N1 is a multiple of BN)
  const unsigned short* Aa = A1;
  const unsigned short* Ab = A2;
  const unsigned short* Bb = Bt;
  if (n0 >= N1){ Aa = A1b; Ab = A1b; Bb = Btb - (long)N1*ldb; }

  // staging source coords, pre-swizzled (involution: bits[5:4] ^= row bits[2:1])
  int srow[2], sce[2];
  #pragma unroll
  for (int q=0;q<2;q++){
    int p  = q*8192 + w*1024 + l*16;
    int sp = p ^ (((p>>7)&3)<<4);
    srow[q] = sp >> 6;
    sce[q]  = (sp & 63) >> 1;
  }

  auto stage = [&](int buf, int kt){
    int k0 = kt*BK;
    const unsigned short* ap; int ko;
    if (k0 < K1){ ap = Aa; ko = k0; } else { ap = Ab; ko = k0 - K1; }
    char* ab = L + buf*BUFSZ;
    char* bb = ab + 16384;
    #pragma unroll
    for (int q=0;q<2;q++)
      glds16(ap + (long)(m0 + srow[q])*lda + ko + sce[q],
             (unsigned short*)(ab + q*8192 + w*1024));
    #pragma unroll
    for (int q=0;q<NBQ;q++)
      glds16(Bb + (long)(n0 + srow[q])*ldb + k0 + sce[q],
             (unsigned short*)(bb + q*8192 + w*1024));
  };

  f32x4 acc[WMF][4];
  #pragma unroll
  for (int m=0;m<WMF;m++)
    #pragma unroll
    for (int n=0;n<4;n++) acc[m][n] = (f32x4){0.f,0.f,0.f,0.f};

  int wr = w / NWC, wc = w % NWC;           // wave tile: rows wr*(WMF*16), cols wc*64
  int fr = l & 15, fq = l >> 4;
  int nk = K / BK;                          // nk >= 32 for all our shapes

  stage(0, 0);
  stage(1, 1);
  if constexpr (S == 4) asm volatile("s_waitcnt vmcnt(4)" ::: "memory");
  else                  asm volatile("s_waitcnt vmcnt(3)" ::: "memory");
  __builtin_amdgcn_s_barrier();
  asm volatile("" ::: "memory");

  int cur = 0;
  for (int kt = 0; kt < nk; ++kt){
    const char* ab = L + cur*BUFSZ;
    const char* bb = ab + 16384;
    short8 af[WMF], bf[4];
    #pragma unroll
    for (int n=0;n<4;n++){
      int r = wc*64 + n*16 + fr;
      bf[n] = *(const short8*)(bb + ((r*64 + fq*16) ^ (((r>>1)&3)<<4)));
    }
    #pragma unroll
    for (int m=0;m<WMF;m++){
      int r = wr*(WMF*16) + m*16 + fr;
      af[m] = *(const short8*)(ab + ((r*64 + fq*16) ^ (((r>>1)&3)<<4)));
    }
    __builtin_amdgcn_s_setprio(1);
    #pragma unroll
    for (int m=0;m<WMF;m++)
      #pragma unroll
      for (int n=0;n<4;n++)
        acc[m][n] = __builtin_amdgcn_mfma_f32_16x16x32_bf16(af[m], bf[n], acc[m][n], 0,0,0);
    __builtin_amdgcn_s_setprio(0);

    __builtin_amdgcn_s_barrier();           // all waves done reading buf[cur]
    asm volatile("" ::: "memory");
    if (kt + 2 < nk){
      stage(cur, kt + 2);                   // refill just-freed buffer
      if constexpr (S == 4) asm volatile("s_waitcnt vmcnt(4)" ::: "memory");  // kt+1 landed
      else                  asm volatile("s_waitcnt vmcnt(3)" ::: "memory");
      __builtin_amdgcn_s_barrier();
      asm volatile("" ::: "memory");
    } else if (kt + 1 < nk){
      asm volatile("s_waitcnt vmcnt(0)" ::: "memory");
      __builtin_amdgcn_s_barrier();
      asm volatile("" ::: "memory");
    }
    cur ^= 1;
  }

  int r0 = m0 + wr*(WMF*16) + (fq << 2);
  int c0 = n0 + wc*64 + fr;
  #pragma unroll
  for (int m=0;m<WMF;m++)
    #pragma unroll
    for (int n=0;n<4;n++){
      int col = c0 + n*16;
      float bv = bias ? bias[col] : 0.f;
      #pragma unroll
      for (int j=0;j<4;j++){
        float v = acc[m][n][j] + bv;
        if (flags & FRELU) v = v > 0.f ? v : 0.f;
        C[(long)(r0 + m*16 + j)*ldc + col] = f2b(v);
      }
    }
}

// ---------------- fused causal flash attention (round-9 proven version) ----------------
// grid (4, B*H), 256 threads: block p handles q-tiles {p, 7-p} (18 KV steps each -> balanced).
__global__ __launch_bounds__(256) void flash_attn(
  const unsigned short* __restrict__ qkv, const unsigned short* __restrict__ vT,
  unsigned short* __restrict__ O)
{
  int p = blockIdx.x, z = blockIdx.y;
  int b = z >> 4, h = z & 15;
  const unsigned short* Vz = vT + (long)z*DH_*T_;

  __shared__ unsigned short Ks[64*64];      // [kv][dh], XOR-swizzled
  __shared__ unsigned short Vs[64*64];      // [dh][kv], XOR-swizzled
  __shared__ unsigned short Ps[4][32][72];

  int t = threadIdx.x, w = t >> 6, l = t & 63;
  int fr = l & 15, fg = l >> 4;
  int srow = t >> 2, sc = (t & 3) * 16;

  for (int rep = 0; rep < 2; ++rep){
    int qt = rep ? (7 - p) : p;
    int q0 = qt*128 + w*32;

    short8 qf[2][2];
    #pragma unroll
    for (int m=0;m<2;m++)
      #pragma unroll
      for (int ks=0;ks<2;ks++)
        qf[m][ks] = *(const short8*)(qkv + ((long)(q0 + m*16 + fr)*B_ + b)*3072 + h*DH_ + ks*32 + fg*8);

    f32x4 oacc[2][4];
    float mr[2][4], lr[2][4];
    #pragma unroll
    for (int m=0;m<2;m++){
      #pragma unroll
      for (int n=0;n<4;n++) oacc[m][n] = (f32x4){0.f,0.f,0.f,0.f};
      #pragma unroll
      for (int j=0;j<4;j++){ mr[m][j] = -1e30f; lr[m][j] = 0.f; }
    }

    int nkv = (qt + 1) * 2;
    for (int kt = 0; kt < nkv; ++kt){
      int kv0 = kt * 64;
      __syncthreads();
      {
        const unsigned short* kg = qkv + ((long)(kv0+srow)*B_ + b)*3072 + 1024 + h*DH_ + sc;
        const unsigned short* vg = Vz + (long)srow*T_ + kv0 + sc;
        int rb = srow*128, sw = (srow & 7) << 4;
        *(u32x4*)((char*)Ks + ((rb + sc*2     ) ^ sw)) = *(const u32x4*)(kg);
        *(u32x4*)((char*)Ks + ((rb + sc*2 + 16) ^ sw)) = *(const u32x4*)(kg + 8);
        *(u32x4*)((char*)Vs + ((rb + sc*2     ) ^ sw)) = *(const u32x4*)(vg);
        *(u32x4*)((char*)Vs + ((rb + sc*2 + 16) ^ sw)) = *(const u32x4*)(vg + 8);
      }
      __syncthreads();

      if (kv0 <= q0 + 31){
        f32x4 sacc[2][4];
        #pragma unroll
        for (int m=0;m<2;m++)
          #pragma unroll
          for (int n=0;n<4;n++) sacc[m][n] = (f32x4){0.f,0.f,0.f,0.f};
        __builtin_amdgcn_s_setprio(1);
        #pragma unroll
        for (int ks=0;ks<2;ks++){
          short8 kf[4];
          #pragma unroll
          for (int n=0;n<4;n++){
            int r = n*16 + fr;
            kf[n] = *(const short8*)((const char*)Ks + ((r*128 + ks*64 + fg*16) ^ ((r & 7) << 4)));
          }
          #pragma unroll
          for (int m=0;m<2;m++)
            #pragma unroll
            for (int n=0;n<4;n++)
              sacc[m][n] = __builtin_amdgcn_mfma_f32_16x16x32_bf16(qf[m][ks], kf[n], sacc[m][n], 0,0,0);
        }
        __builtin_amdgcn_s_setprio(0);

        #pragma unroll
        for (int m=0;m<2;m++)
          #pragma unroll
          for (int j=0;j<4;j++){
            int qg = q0 + m*16 + fg*4 + j;
            float vmax = -1e30f;
            #pragma unroll
            for (int n=0;n<4;n++){
              int kg = kv0 + n*16 + fr;
              float s = (kg <= qg) ? sacc[m][n][j]*0.125f : -1e30f;
              sacc[m][n][j] = s;
              vmax = fmaxf(vmax, s);
            }
            #pragma unroll
            for (int msk=1; msk<16; msk<<=1) vmax = fmaxf(vmax, __shfl_xor(vmax, msk));
            float mnew = fmaxf(mr[m][j], vmax);
            float sc_o = __expf(mr[m][j] - mnew);
            mr[m][j] = mnew;
            float rsum = 0.f;
            #pragma unroll
            for (int n=0;n<4;n++){
              float pv = __expf(sacc[m][n][j] - mnew);
              sacc[m][n][j] = pv;
              rsum += pv;
            }
            #pragma unroll
            for (int msk=1; msk<16; msk<<=1) rsum += __shfl_xor(rsum, msk);
            lr[m][j] = lr[m][j]*sc_o + rsum;
            #pragma unroll
            for (int n=0;n<4;n++) oacc[m][n][j] *= sc_o;
          }

        #pragma unroll
        for (int m=0;m<2;m++)
          #pragma unroll
          for (int n=0;n<4;n++)
            #pragma unroll
            for (int j=0;j<4;j++)
              Ps[w][m*16 + fg*4 + j][n*16 + fr] = f2b(sacc[m][n][j]);

        __builtin_amdgcn_s_setprio(1);
        #pragma unroll
        for (int ks=0;ks<2;ks++){
          short8 pf[2], vf[4];
          #pragma unroll
          for (int m=0;m<2;m++) pf[m] = *(const short8*)&Ps[w][m*16+fr][ks*32+fg*8];
          #pragma unroll
          for (int n=0;n<4;n++){
            int r = n*16 + fr;
            vf[n] = *(const short8*)((const char*)Vs + ((r*128 + ks*64 + fg*16) ^ ((r & 7) << 4)));
          }
          #pragma unroll
          for (int m=0;m<2;m++)
            #pragma unroll
            for (int n=0;n<4;n++)
              oacc[m][n] = __builtin_amdgcn_mfma_f32_16x16x32_bf16(pf[m], vf[n], oacc[m][n], 0,0,0);
        }
        __builtin_amdgcn_s_setprio(0);
      }
    }

    #pragma unroll
    for (int m=0;m<2;m++)
      #pragma unroll
      for (int j=0;j<4;j++){
        float inv = 1.f / lr[m][j];
        long i = q0 + m*16 + fg*4 + j;
        #pragma unroll
        for (int n=0;n<4;n++)
          O[(i*B_ + b)*(long)D_ + h*DH_ + n*16 + fr] = f2b(oacc[m][n][j] * inv);
      }
  }
}

// ---------------- fused LN1 + raw cast (one pass over x) ----------------
__global__ __launch_bounds__(256) void ln_cast(const float* __restrict__ X,
    const float* __restrict__ g, const float* __restrict__ bta,
    unsigned short* __restrict__ xn, unsigned short* __restrict__ xbf)
{
  long row = blockIdx.x;
  int t = threadIdx.x;
  f32x4 xv = ((const f32x4*)(X + row*D_))[t];
  float s = xv[0]+xv[1]+xv[2]+xv[3];
  float q = xv[0]*xv[0]+xv[1]*xv[1]+xv[2]*xv[2]+xv[3]*xv[3];
  #pragma unroll
  for (int o=32;o;o>>=1){ s += __shfl_xor(s,o); q += __shfl_xor(q,o); }
  __shared__ float rs[4], rq[4];
  int w = t >> 6;
  if ((t & 63) == 0){ rs[w]=s; rq[w]=q; }
  __syncthreads();
  s = rs[0]+rs[1]+rs[2]+rs[3];
  q = rq[0]+rq[1]+rq[2]+rq[3];
  float mean = s * (1.f/D_);
  float var  = q * (1.f/D_) - mean*mean;
  float rstd = rsqrtf(var + 1e-5f);
  f32x4 gv = ((const f32x4*)g)[t];
  f32x4 bv = ((const f32x4*)bta)[t];
  us4 o, raw;
  #pragma unroll
  for (int jj=0;jj<4;jj++){
    o[jj]   = f2b((xv[jj]-mean)*rstd*gv[jj] + bv[jj]);
    raw[jj] = f2b(xv[jj]);
  }
  ((us4*)(xn  + row*D_))[t] = o;
  ((us4*)(xbf + row*D_))[t] = raw;
}

// ---------------- weight transpose + cast: dst[n*ldd + k] = bf16(src[k][n]) ----------------
__global__ __launch_bounds__(256) void tr_f2b(const float* __restrict__ src,
    unsigned short* __restrict__ dst, int N, long ldd)
{
  __shared__ float tile[32][33];
  int k0 = blockIdx.x*32, n0 = blockIdx.y*32;
  int tx = threadIdx.x & 31, ty = threadIdx.x >> 5;
  #pragma unroll
  for (int i=0;i<4;i++)
    tile[ty+i*8][tx] = src[(long)(k0+ty+i*8)*N + n0 + tx];
  __syncthreads();
  #pragma unroll
  for (int i=0;i<4;i++)
    dst[(long)(n0+ty+i*8)*ldd + k0 + tx] = f2b(tile[tx][ty+i*8]);
}

// ---------------- batched gate-weight transpose: z=0..3 -> BtRZ quadrants, z=4,5 -> W2g/U2g ----------------
__global__ __launch_bounds__(256) void tr_gate(const float* __restrict__ gW,
    const float* __restrict__ gU, unsigned short* __restrict__ Wb)
{
  __shared__ float tile[32][33];
  int z = blockIdx.z;
  int c = z >> 1;
  const float* src = ((z & 1) ? gU : gW) + (size_t)c*1048576;
  unsigned short* dst; long ldd;
  if (c < 2){ dst = Wb + (size_t)c*(1024*2048) + (z&1)*1024; ldd = 2048; }
  else      { dst = Wb + (size_t)(4 + (z&1))*1048576;        ldd = 1024; }
  int k0 = blockIdx.x*32, n0 = blockIdx.y*32;
  int tx = threadIdx.x & 31, ty = threadIdx.x >> 5;
  #pragma unroll
  for (int i=0;i<4;i++)
    tile[ty+i*8][tx] = src[(long)(k0+ty+i*8)*1024 + n0 + tx];
  __syncthreads();
  #pragma unroll
  for (int i=0;i<4;i++)
    dst[(long)(n0+ty+i*8)*ldd + k0 + tx] = f2b(tile[tx][ty+i*8]);
}

// ---------------- V^T build from qkv: vT[z][dh][t] ----------------
__global__ __launch_bounds__(256) void build_vT(const unsigned short* __restrict__ vsrc,
                                                unsigned short* __restrict__ vT)
{
  __shared__ unsigned short tile[32][33];
  int z = blockIdx.z, b = z >> 4, h = z & 15;
  int t0 = blockIdx.x*32, d0 = blockIdx.y*32;
  int tx = threadIdx.x & 31, ty = threadIdx.x >> 5;
  #pragma unroll
  for (int i=0;i<4;i++)
    tile[ty+i*8][tx] = vsrc[((long)(t0+ty+i*8)*B_ + b)*3072 + h*DH_ + d0 + tx];
  __syncthreads();
  #pragma unroll
  for (int i=0;i<4;i++)
    vT[(long)z*DH_*T_ + (long)(d0+ty+i*8)*T_ + t0 + tx] = tile[tx][ty+i*8];
}

// ---------------- GRU gate combine (+ optional fused LayerNorm of the gated output) ----------------
// yx: [m][2048] = (ya | xb). grid MUST be MROWS blocks (1 row/block).
__global__ __launch_bounds__(256) void gru_combine(
  const unsigned short* __restrict__ rz,
  const unsigned short* __restrict__ yx,
  const float* __restrict__ xin, const float* __restrict__ bz,
  float* __restrict__ of, unsigned short* __restrict__ ob,
  const float* __restrict__ lng, const float* __restrict__ lnb,
  unsigned short* __restrict__ sn)
{
  int t = threadIdx.x;
  long row = blockIdx.x;
  long i = row*1024 + t*4;
  int col = t*4;
  us4 r4 = *(const us4*)(rz + row*2048 + col);
  us4 z4 = *(const us4*)(rz + row*2048 + 1024 + col);
  us4 a4 = *(const us4*)(yx + row*2048 + col);
  us4 b4 = *(const us4*)(yx + row*2048 + 1024 + col);
  f32x4 xv = *(const f32x4*)(xin + i);
  f32x4 bzv = *(const f32x4*)(bz + col);
  f32x4 o;
  #pragma unroll
  for (int jj=0;jj<4;jj++){
    float r = 1.f/(1.f + __expf(-b2f(r4[jj])));
    float z = 1.f/(1.f + __expf(-(b2f(z4[jj]) + bzv[jj] - 0.1f)));
    float h = tanhf(b2f(a4[jj]) + r*b2f(b4[jj]));
    o[jj] = (1.f - z)*xv[jj] + z*h;
  }
  *(f32x4*)(of+i) = o;
  if (ob){
    us4 q;
    #pragma unroll
    for (int jj=0;jj<4;jj++) q[jj] = f2b(o[jj]);
    *(us4*)(ob+i) = q;
  }
  if (sn){                                  // fused LN over this row's gated output
    float s = o[0]+o[1]+o[2]+o[3];
    float q = o[0]*o[0]+o[1]*o[1]+o[2]*o[2]+o[3]*o[3];
    #pragma unroll
    for (int off=32;off;off>>=1){ s += __shfl_xor(s,off); q += __shfl_xor(q,off); }
    __shared__ float rs[4], rq[4];
    int w = t >> 6;
    if ((t & 63) == 0){ rs[w]=s; rq[w]=q; }
    __syncthreads();
    s = rs[0]+rs[1]+rs[2]+rs[3];
    q = rq[0]+rq[1]+rq[2]+rq[3];
    float mean = s * (1.f/D_);
    float var  = q * (1.f/D_) - mean*mean;
    float rstd = rsqrtf(var + 1e-5f);
    f32x4 gv = ((const f32x4*)lng)[t];
    f32x4 bv = ((const f32x4*)lnb)[t];
    us4 oq;
    #pragma unroll
    for (int jj=0;jj<4;jj++) oq[jj] = f2b((o[jj]-mean)*rstd*gv[jj] + bv[jj]);
    *(us4*)(sn+i) = oq;
  }
}

// =======================================================================
extern "C" void kernel_launch(void* const* d_in, const int* in_sizes, int n_in,
                              void* d_out, int out_size, void* d_ws, size_t ws_size,
                              hipStream_t stream)
{
  const float* x    = (const float*)d_in[0];
  const float* Wq   = (const float*)d_in[1];
  const float* Wk   = (const float*)d_in[2];
  const float* Wv   = (const float*)d_in[3];
  const float* Wo   = (const float*)d_in[4];
  const float* ln1g = (const float*)d_in[5];
  const float* ln1b = (const float*)d_in[6];
  const float* W1   = (const float*)d_in[7];
  const float* b1   = (const float*)d_in[8];
  const float* W2   = (const float*)d_in[9];
  const float* b2   = (const float*)d_in[10];
  const float* ln2g = (const float*)d_in[11];
  const float* ln2b = (const float*)d_in[12];
  const float* g1W  = (const float*)d_in[13];
  const float* g1U  = (const float*)d_in[14];
  const float* g1bz = (const float*)d_in[15];
  const float* g2W  = (const float*)d_in[16];
  const float* g2U  = (const float*)d_in[17];
  const float* g2bz = (const float*)d_in[18];
  float* out = (float*)d_out;

  const size_t MB = 1u << 20;
  if (ws_size < 144*MB) return;
  char* base = (char*)d_ws;

  (void)hipFuncSetAttribute((const void*)gemm256<256>,
                            hipFuncAttributeMaxDynamicSharedMemorySize, 65536);
  (void)hipFuncSetAttribute((const void*)gemm256<128>,
                            hipFuncAttributeMaxDynamicSharedMemorySize, 49152);

  unsigned short* W    = (unsigned short*)(base);           // 16MB weight staging (phase-multiplexed)
  unsigned short* x_bf = (unsigned short*)(base + 16*MB);   // raw x bf16; dead after gate1 -> reused as sn
  unsigned short* sbf  = (unsigned short*)(base + 32*MB);   // src bf16 (gate1 out)
  unsigned short* src2 = (unsigned short*)(base + 48*MB);   // attn@Wo -> later ffb
  unsigned short* qkv  = (unsigned short*)(base + 64*MB);   // [8192][3072] 48MB
  unsigned short* vT   = (unsigned short*)(base + 112*MB);  // 16MB (dead after flash_attn)
  unsigned short* attn = (unsigned short*)(base + 128*MB);  // 16MB (also xn before QKV)
  unsigned short* xn   = attn;
  unsigned short* rz   = (unsigned short*)(base + 64*MB);   // [8192][2048] 32MB
  unsigned short* yx   = (unsigned short*)(base + 96*MB);   // [8192][2048] 32MB (ya|xb)
  unsigned short* sn   = x_bf;                              // LN2 output (x_bf dead by then)
  unsigned short* ff1  = (unsigned short*)(base + 80*MB);   // [8192][4096] 64MB (dead before gate2)
  unsigned short* ffb  = src2;

  const size_t E1M = 1048576;               // elements per 2MB
  unsigned short* BtRZ = W;                 // [2048][2048] 8MB (+ W2g/U2g at 4,5 E1M)
  unsigned short* W2g  = W + 4*E1M;
  unsigned short* U2g  = W + 5*E1M;
  unsigned short* W1T  = W;                 // FFN: [4096][1024] 8MB
  unsigned short* W2T  = W + 4*E1M;         // [1024][4096] 8MB
  unsigned short* Wqkv = W;                 // [3072][1024] 6MB
  unsigned short* WoT  = W + 3*E1M;

  const int NOSPLIT = 1 << 30;
  dim3 blk(256);
  auto G2 = [&](const unsigned short* A1, const unsigned short* A2, int K1, long lda,
                const unsigned short* Bt, long ldb, unsigned short* C, long ldc,
                const float* bias, int M, int N, int K, int flags,
                const unsigned short* A1b, const unsigned short* Btb, int N1){
    gemm256<256><<<dim3(N/256, M/256), dim3(512), 65536, stream>>>(
        A1,A2,K1,lda,Bt,ldb,C,ldc,bias,K,flags,A1b,Btb,N1);
  };
  auto G2n = [&](const unsigned short* A1, const unsigned short* A2, int K1, long lda,
                 const unsigned short* Bt, long ldb, unsigned short* C, long ldc,
                 const float* bias, int M, int N, int K, int flags){
    gemm256<128><<<dim3(N/128, M/256), dim3(512), 49152, stream>>>(
        A1,A2,K1,lda,Bt,ldb,C,ldc,bias,K,flags,A1,Bt,NOSPLIT);
  };

  // ---- phase 0: attention weights + fused LN1/cast ----
  tr_f2b<<<dim3(32,32), blk, 0, stream>>>(Wq, Wqkv,          D_, D_);
  tr_f2b<<<dim3(32,32), blk, 0, stream>>>(Wk, Wqkv + 1*E1M,  D_, D_);
  tr_f2b<<<dim3(32,32), blk, 0, stream>>>(Wv, Wqkv + 2*E1M,  D_, D_);
  tr_f2b<<<dim3(32,32), blk, 0, stream>>>(Wo, WoT,           D_, D_);
  ln_cast<<<dim3(MROWS), blk, 0, stream>>>(x, ln1g, ln1b, xn, x_bf);

  // ---- phase 1: QKV (split: QK as one full 256-block BN=256 round, V as a 256-block BN=128 round)
  G2(xn, xn, D_, D_, Wqkv, D_, qkv, 3072, nullptr, MROWS, 2048, D_, 0, xn, Wqkv, NOSPLIT);
  G2n(xn, xn, D_, D_, Wqkv + 2*E1M, D_, qkv + 2048, 3072, nullptr, MROWS, 1024, D_, 0);
  build_vT<<<dim3(32,2,128), blk, 0, stream>>>(qkv + 2048, vT);
  flash_attn<<<dim3(4, B_*H_), blk, 0, stream>>>(qkv, vT, attn);
  G2n(attn, attn, D_, D_, WoT, D_, src2, D_, nullptr, MROWS, D_, D_, 0);

  // ---- phase 2: GRU gate 1 (x-path = x_bf, y-path = src2), LN2 fused into combine ----
  tr_gate<<<dim3(32,32,6), blk, 0, stream>>>(g1W, g1U, W);
  G2(src2, x_bf, D_, D_, BtRZ, 2048, rz, 2048, nullptr, MROWS, 2048, 2048, 0, src2, BtRZ, NOSPLIT);
  G2(src2, src2, D_, D_, W2g, D_, yx, 2048, nullptr, MROWS, 2048, D_, 0, x_bf, U2g, 1024);
  gru_combine<<<dim3(MROWS), blk, 0, stream>>>(rz, yx, x, g1bz, out, sbf, ln2g, ln2b, sn);

  // ---- phase 3: FFN ----
  tr_f2b<<<dim3(32,128), blk, 0, stream>>>(W1, W1T, FF_, D_);
  tr_f2b<<<dim3(128,32), blk, 0, stream>>>(W2, W2T, D_, FF_);
  G2(sn, sn, D_, D_, W1T, D_, ff1, FF_, b1, MROWS, FF_, D_, FRELU, sn, W1T, NOSPLIT);
  G2n(ff1, ff1, FF_, FF_, W2T, FF_, ffb, D_, b2, MROWS, D_, FF_, 0);

  // ---- phase 4: GRU gate 2 (x-path = sbf, y-path = ffb) ----
  tr_gate<<<dim3(32,32,6), blk, 0, stream>>>(g2W, g2U, W);
  G2(ffb, sbf, D_, D_, BtRZ, 2048, rz, 2048, nullptr, MROWS, 2048, 2048, 0, ffb, BtRZ, NOSPLIT);
  G2(ffb, ffb, D_, D_, W2g, D_, yx, 2048, nullptr, MROWS, 2048, D_, 0, sbf, U2g, 1024);
  gru_combine<<<dim3(MROWS), blk, 0, stream>>>(rz, yx, out, g2bz, out, nullptr, nullptr, nullptr, nullptr);
}

// Round 20
// 690.235 us; speedup vs baseline: 1.0147x; 1.0147x over previous
//
#include <hip/hip_runtime.h>
#include <hip/hip_bf16.h>

#define T_  1024
#define B_  8
#define D_  1024
#define H_  16
#define DH_ 64
#define FF_ 4096
#define MROWS (T_*B_)   // 8192 token rows, row m = t*B + b

typedef __attribute__((ext_vector_type(8))) short short8;     // 8 bf16 MFMA operand
typedef __attribute__((ext_vector_type(4))) float f32x4;
typedef __attribute__((ext_vector_type(4))) unsigned short us4;
typedef __attribute__((ext_vector_type(4))) unsigned int  u32x4;

__device__ __forceinline__ unsigned short f2b(float f){
  unsigned int u = __builtin_bit_cast(unsigned int, f);
  u += 0x7FFFu + ((u >> 16) & 1u);          // RNE
  return (unsigned short)(u >> 16);
}
__device__ __forceinline__ float b2f(unsigned short h){
  unsigned int u = ((unsigned int)h) << 16;
  return __builtin_bit_cast(float, u);
}

__device__ __forceinline__ void glds16(const unsigned short* g, unsigned short* l){
  __builtin_amdgcn_global_load_lds(
    (const __attribute__((address_space(1))) unsigned int*)g,
    (__attribute__((address_space(3))) unsigned int*)l, 16, 0, 0);
}

enum { FRELU=1 };

// ================= gemm256<BN>: 256xBN tile, BK=32, 8 waves, 4-buffer rotating =================
// (round-16/18 proven 691us version) prefetch-3 counted pipeline; vmcnt never drains to 0 in
// steady state. LDS swizzle: byte bits[5:4] ^= row bits[2:1] (conflict-free 2 lanes/bank).
// BN=256: wave tile 128x64 (acc 8x4) — the efficient shape (12 ds_read : 32 MFMA per step).
// BN=128: wave tile 128x32 (acc 8x2) — N=1024 shapes only.
// Exploration record (do not retry): 2ph-split -7%, BN=128 wide-N -11%, (512,4) spills 4.7x,
// 2-buffer co-residency -1.4%. 4-buffer/1-block-CU is this family's optimum.
// N-split option (N1): blocks with n0>=N1 use (A1b, Btb) — fuses two GEMMs into one launch.
template<int BN>
__global__ __launch_bounds__(512, 2) void gemm256(
    const unsigned short* __restrict__ A1, const unsigned short* __restrict__ A2,
    int K1, long lda,
    const unsigned short* __restrict__ Bt, long ldb,
    unsigned short* __restrict__ C, long ldc,
    const float* __restrict__ bias, int K, int flags,
    const unsigned short* __restrict__ A1b, const unsigned short* __restrict__ Btb,
    int N1)
{
  constexpr int BM = 256, BK = 32;
  constexpr int NBQ = BN/128;               // B-loads per thread per stage
  constexpr int S   = 2 + NBQ;              // total loads per thread per stage
  constexpr int WN  = BN/64;                // B fragments per wave
  constexpr int BUFSZ = 16384 + BN*64;      // A 16KB + B
  extern __shared__ char L[];               // 4 x BUFSZ

  int t = threadIdx.x, w = t >> 6, l = t & 63;

  // T1: XCD-chunked swizzle (identity unless nwg%8==0; all our grids are %8)
  int nx = gridDim.x;
  int nwg = nx * gridDim.y;
  int lin = blockIdx.y*nx + blockIdx.x;
  if (!(nwg & 7)) lin = (lin & 7)*(nwg >> 3) + (lin >> 3);
  int bx = lin % nx, by = lin / nx;
  int m0 = by*BM, n0 = bx*BN;

  // N-split operand selection (block-uniform; N1 is a multiple of BN)
  const unsigned short* Aa = A1;
  const unsigned short* Ab = A2;
  const unsigned short* Bb = Bt;
  if (n0 >= N1){ Aa = A1b; Ab = A1b; Bb = Btb - (long)N1*ldb; }

  // staging source coords, pre-swizzled (involution: bits[5:4] ^= row bits[2:1])
  int srow[2], sce[2];
  #pragma unroll
  for (int q=0;q<2;q++){
    int p  = q*8192 + w*1024 + l*16;
    int sp = p ^ (((p>>7)&3)<<4);
    srow[q] = sp >> 6;
    sce[q]  = (sp & 63) >> 1;
  }

  auto stage = [&](int buf, int kt){
    int k0 = kt*BK;
    const unsigned short* ap; int ko;
    if (k0 < K1){ ap = Aa; ko = k0; } else { ap = Ab; ko = k0 - K1; }
    char* ab = L + buf*BUFSZ;
    char* bb = ab + 16384;
    #pragma unroll
    for (int q=0;q<2;q++)
      glds16(ap + (long)(m0 + srow[q])*lda + ko + sce[q],
             (unsigned short*)(ab + q*8192 + w*1024));
    #pragma unroll
    for (int q=0;q<NBQ;q++)
      glds16(Bb + (long)(n0 + srow[q])*ldb + k0 + sce[q],
             (unsigned short*)(bb + q*8192 + w*1024));
  };

  f32x4 acc[8][WN];
  #pragma unroll
  for (int m=0;m<8;m++)
    #pragma unroll
    for (int n=0;n<WN;n++) acc[m][n] = (f32x4){0.f,0.f,0.f,0.f};

  int wr = w >> 2, wc = w & 3;              // wave tile: rows wr*128, cols wc*(BN/4)
  int fr = l & 15, fq = l >> 4;
  int nk = K / BK;                          // nk >= 32 for all our shapes

  stage(0, 0);
  stage(1, 1);
  stage(2, 2);
  if constexpr (S == 4) asm volatile("s_waitcnt vmcnt(8)" ::: "memory");
  else                  asm volatile("s_waitcnt vmcnt(6)" ::: "memory");
  __builtin_amdgcn_s_barrier();
  asm volatile("" ::: "memory");

  int cur = 0;
  for (int kt = 0; kt < nk; ++kt){
    if (kt + 3 < nk) stage((cur + 3) & 3, kt + 3);   // G-loads fly under MFMA below

    const char* ab = L + cur*BUFSZ;
    const char* bb = ab + 16384;
    short8 af[8], bf[WN];
    #pragma unroll
    for (int n=0;n<WN;n++){
      int r = wc*(BN/4) + n*16 + fr;
      bf[n] = *(const short8*)(bb + ((r*64 + fq*16) ^ (((r>>1)&3)<<4)));
    }
    #pragma unroll
    for (int m=0;m<8;m++){
      int r = wr*128 + m*16 + fr;
      af[m] = *(const short8*)(ab + ((r*64 + fq*16) ^ (((r>>1)&3)<<4)));
    }
    __builtin_amdgcn_s_setprio(1);
    #pragma unroll
    for (int m=0;m<8;m++)
      #pragma unroll
      for (int n=0;n<WN;n++)
        acc[m][n] = __builtin_amdgcn_mfma_f32_16x16x32_bf16(af[m], bf[n], acc[m][n], 0,0,0);
    __builtin_amdgcn_s_setprio(0);

    int c = nk - 1 - kt; if (c > 3) c = 3;           // stages still in flight
    if (c == 3){
      if constexpr (S == 4) asm volatile("s_waitcnt vmcnt(8)" ::: "memory");
      else                  asm volatile("s_waitcnt vmcnt(6)" ::: "memory");
    } else if (c == 2){
      if constexpr (S == 4) asm volatile("s_waitcnt vmcnt(4)" ::: "memory");
      else                  asm volatile("s_waitcnt vmcnt(3)" ::: "memory");
    } else if (c == 1){
      asm volatile("s_waitcnt vmcnt(0)" ::: "memory");
    }
    if (c > 0){
      __builtin_amdgcn_s_barrier();
      asm volatile("" ::: "memory");
    }
    cur = (cur + 1) & 3;
  }

  int r0 = m0 + wr*128 + (fq << 2);
  int c0 = n0 + wc*(BN/4) + fr;
  #pragma unroll
  for (int m=0;m<8;m++)
    #pragma unroll
    for (int n=0;n<WN;n++){
      int col = c0 + n*16;
      float bv = bias ? bias[col] : 0.f;
      #pragma unroll
      for (int j=0;j<4;j++){
        float v = acc[m][n][j] + bv;
        if (flags & FRELU) v = v > 0.f ? v : 0.f;
        C[(long)(r0 + m*16 + j)*ldc + col] = f2b(v);
      }
    }
}

// ---------------- fused causal flash attention (round-9 proven version) ----------------
// grid (4, B*H), 256 threads: block p handles q-tiles {p, 7-p} (18 KV steps each -> balanced).
__global__ __launch_bounds__(256) void flash_attn(
  const unsigned short* __restrict__ qkv, const unsigned short* __restrict__ vT,
  unsigned short* __restrict__ O)
{
  int p = blockIdx.x, z = blockIdx.y;
  int b = z >> 4, h = z & 15;
  const unsigned short* Vz = vT + (long)z*DH_*T_;

  __shared__ unsigned short Ks[64*64];      // [kv][dh], XOR-swizzled
  __shared__ unsigned short Vs[64*64];      // [dh][kv], XOR-swizzled
  __shared__ unsigned short Ps[4][32][72];

  int t = threadIdx.x, w = t >> 6, l = t & 63;
  int fr = l & 15, fg = l >> 4;
  int srow = t >> 2, sc = (t & 3) * 16;

  for (int rep = 0; rep < 2; ++rep){
    int qt = rep ? (7 - p) : p;
    int q0 = qt*128 + w*32;

    short8 qf[2][2];
    #pragma unroll
    for (int m=0;m<2;m++)
      #pragma unroll
      for (int ks=0;ks<2;ks++)
        qf[m][ks] = *(const short8*)(qkv + ((long)(q0 + m*16 + fr)*B_ + b)*3072 + h*DH_ + ks*32 + fg*8);

    f32x4 oacc[2][4];
    float mr[2][4], lr[2][4];
    #pragma unroll
    for (int m=0;m<2;m++){
      #pragma unroll
      for (int n=0;n<4;n++) oacc[m][n] = (f32x4){0.f,0.f,0.f,0.f};
      #pragma unroll
      for (int j=0;j<4;j++){ mr[m][j] = -1e30f; lr[m][j] = 0.f; }
    }

    int nkv = (qt + 1) * 2;
    for (int kt = 0; kt < nkv; ++kt){
      int kv0 = kt * 64;
      __syncthreads();
      {
        const unsigned short* kg = qkv + ((long)(kv0+srow)*B_ + b)*3072 + 1024 + h*DH_ + sc;
        const unsigned short* vg = Vz + (long)srow*T_ + kv0 + sc;
        int rb = srow*128, sw = (srow & 7) << 4;
        *(u32x4*)((char*)Ks + ((rb + sc*2     ) ^ sw)) = *(const u32x4*)(kg);
        *(u32x4*)((char*)Ks + ((rb + sc*2 + 16) ^ sw)) = *(const u32x4*)(kg + 8);
        *(u32x4*)((char*)Vs + ((rb + sc*2     ) ^ sw)) = *(const u32x4*)(vg);
        *(u32x4*)((char*)Vs + ((rb + sc*2 + 16) ^ sw)) = *(const u32x4*)(vg + 8);
      }
      __syncthreads();

      if (kv0 <= q0 + 31){
        f32x4 sacc[2][4];
        #pragma unroll
        for (int m=0;m<2;m++)
          #pragma unroll
          for (int n=0;n<4;n++) sacc[m][n] = (f32x4){0.f,0.f,0.f,0.f};
        __builtin_amdgcn_s_setprio(1);
        #pragma unroll
        for (int ks=0;ks<2;ks++){
          short8 kf[4];
          #pragma unroll
          for (int n=0;n<4;n++){
            int r = n*16 + fr;
            kf[n] = *(const short8*)((const char*)Ks + ((r*128 + ks*64 + fg*16) ^ ((r & 7) << 4)));
          }
          #pragma unroll
          for (int m=0;m<2;m++)
            #pragma unroll
            for (int n=0;n<4;n++)
              sacc[m][n] = __builtin_amdgcn_mfma_f32_16x16x32_bf16(qf[m][ks], kf[n], sacc[m][n], 0,0,0);
        }
        __builtin_amdgcn_s_setprio(0);

        #pragma unroll
        for (int m=0;m<2;m++)
          #pragma unroll
          for (int j=0;j<4;j++){
            int qg = q0 + m*16 + fg*4 + j;
            float vmax = -1e30f;
            #pragma unroll
            for (int n=0;n<4;n++){
              int kg = kv0 + n*16 + fr;
              float s = (kg <= qg) ? sacc[m][n][j]*0.125f : -1e30f;
              sacc[m][n][j] = s;
              vmax = fmaxf(vmax, s);
            }
            #pragma unroll
            for (int msk=1; msk<16; msk<<=1) vmax = fmaxf(vmax, __shfl_xor(vmax, msk));
            float mnew = fmaxf(mr[m][j], vmax);
            float sc_o = __expf(mr[m][j] - mnew);
            mr[m][j] = mnew;
            float rsum = 0.f;
            #pragma unroll
            for (int n=0;n<4;n++){
              float pv = __expf(sacc[m][n][j] - mnew);
              sacc[m][n][j] = pv;
              rsum += pv;
            }
            #pragma unroll
            for (int msk=1; msk<16; msk<<=1) rsum += __shfl_xor(rsum, msk);
            lr[m][j] = lr[m][j]*sc_o + rsum;
            #pragma unroll
            for (int n=0;n<4;n++) oacc[m][n][j] *= sc_o;
          }

        #pragma unroll
        for (int m=0;m<2;m++)
          #pragma unroll
          for (int n=0;n<4;n++)
            #pragma unroll
            for (int j=0;j<4;j++)
              Ps[w][m*16 + fg*4 + j][n*16 + fr] = f2b(sacc[m][n][j]);

        __builtin_amdgcn_s_setprio(1);
        #pragma unroll
        for (int ks=0;ks<2;ks++){
          short8 pf[2], vf[4];
          #pragma unroll
          for (int m=0;m<2;m++) pf[m] = *(const short8*)&Ps[w][m*16+fr][ks*32+fg*8];
          #pragma unroll
          for (int n=0;n<4;n++){
            int r = n*16 + fr;
            vf[n] = *(const short8*)((const char*)Vs + ((r*128 + ks*64 + fg*16) ^ ((r & 7) << 4)));
          }
          #pragma unroll
          for (int m=0;m<2;m++)
            #pragma unroll
            for (int n=0;n<4;n++)
              oacc[m][n] = __builtin_amdgcn_mfma_f32_16x16x32_bf16(pf[m], vf[n], oacc[m][n], 0,0,0);
        }
        __builtin_amdgcn_s_setprio(0);
      }
    }

    #pragma unroll
    for (int m=0;m<2;m++)
      #pragma unroll
      for (int j=0;j<4;j++){
        float inv = 1.f / lr[m][j];
        long i = q0 + m*16 + fg*4 + j;
        #pragma unroll
        for (int n=0;n<4;n++)
          O[(i*B_ + b)*(long)D_ + h*DH_ + n*16 + fr] = f2b(oacc[m][n][j] * inv);
      }
  }
}

// ---------------- fused LN1 + raw cast (one pass over x) ----------------
__global__ __launch_bounds__(256) void ln_cast(const float* __restrict__ X,
    const float* __restrict__ g, const float* __restrict__ bta,
    unsigned short* __restrict__ xn, unsigned short* __restrict__ xbf)
{
  long row = blockIdx.x;
  int t = threadIdx.x;
  f32x4 xv = ((const f32x4*)(X + row*D_))[t];
  float s = xv[0]+xv[1]+xv[2]+xv[3];
  float q = xv[0]*xv[0]+xv[1]*xv[1]+xv[2]*xv[2]+xv[3]*xv[3];
  #pragma unroll
  for (int o=32;o;o>>=1){ s += __shfl_xor(s,o); q += __shfl_xor(q,o); }
  __shared__ float rs[4], rq[4];
  int w = t >> 6;
  if ((t & 63) == 0){ rs[w]=s; rq[w]=q; }
  __syncthreads();
  s = rs[0]+rs[1]+rs[2]+rs[3];
  q = rq[0]+rq[1]+rq[2]+rq[3];
  float mean = s * (1.f/D_);
  float var  = q * (1.f/D_) - mean*mean;
  float rstd = rsqrtf(var + 1e-5f);
  f32x4 gv = ((const f32x4*)g)[t];
  f32x4 bv = ((const f32x4*)bta)[t];
  us4 o, raw;
  #pragma unroll
  for (int jj=0;jj<4;jj++){
    o[jj]   = f2b((xv[jj]-mean)*rstd*gv[jj] + bv[jj]);
    raw[jj] = f2b(xv[jj]);
  }
  ((us4*)(xn  + row*D_))[t] = o;
  ((us4*)(xbf + row*D_))[t] = raw;
}

// ---------------- weight transpose + cast: dst[n*ldd + k] = bf16(src[k][n]) ----------------
__global__ __launch_bounds__(256) void tr_f2b(const float* __restrict__ src,
    unsigned short* __restrict__ dst, int N, long ldd)
{
  __shared__ float tile[32][33];
  int k0 = blockIdx.x*32, n0 = blockIdx.y*32;
  int tx = threadIdx.x & 31, ty = threadIdx.x >> 5;
  #pragma unroll
  for (int i=0;i<4;i++)
    tile[ty+i*8][tx] = src[(long)(k0+ty+i*8)*N + n0 + tx];
  __syncthreads();
  #pragma unroll
  for (int i=0;i<4;i++)
    dst[(long)(n0+ty+i*8)*ldd + k0 + tx] = f2b(tile[tx][ty+i*8]);
}

// ---------------- batched gate-weight transpose: z=0..3 -> BtRZ quadrants, z=4,5 -> W2g/U2g ----------------
__global__ __launch_bounds__(256) void tr_gate(const float* __restrict__ gW,
    const float* __restrict__ gU, unsigned short* __restrict__ Wb)
{
  __shared__ float tile[32][33];
  int z = blockIdx.z;
  int c = z >> 1;
  const float* src = ((z & 1) ? gU : gW) + (size_t)c*1048576;
  unsigned short* dst; long ldd;
  if (c < 2){ dst = Wb + (size_t)c*(1024*2048) + (z&1)*1024; ldd = 2048; }
  else      { dst = Wb + (size_t)(4 + (z&1))*1048576;        ldd = 1024; }
  int k0 = blockIdx.x*32, n0 = blockIdx.y*32;
  int tx = threadIdx.x & 31, ty = threadIdx.x >> 5;
  #pragma unroll
  for (int i=0;i<4;i++)
    tile[ty+i*8][tx] = src[(long)(k0+ty+i*8)*1024 + n0 + tx];
  __syncthreads();
  #pragma unroll
  for (int i=0;i<4;i++)
    dst[(long)(n0+ty+i*8)*ldd + k0 + tx] = f2b(tile[tx][ty+i*8]);
}

// ---------------- V^T build from qkv: vT[z][dh][t] ----------------
__global__ __launch_bounds__(256) void build_vT(const unsigned short* __restrict__ vsrc,
                                                unsigned short* __restrict__ vT)
{
  __shared__ unsigned short tile[32][33];
  int z = blockIdx.z, b = z >> 4, h = z & 15;
  int t0 = blockIdx.x*32, d0 = blockIdx.y*32;
  int tx = threadIdx.x & 31, ty = threadIdx.x >> 5;
  #pragma unroll
  for (int i=0;i<4;i++)
    tile[ty+i*8][tx] = vsrc[((long)(t0+ty+i*8)*B_ + b)*3072 + h*DH_ + d0 + tx];
  __syncthreads();
  #pragma unroll
  for (int i=0;i<4;i++)
    vT[(long)z*DH_*T_ + (long)(d0+ty+i*8)*T_ + t0 + tx] = tile[tx][ty+i*8];
}

// ---------------- GRU gate combine (+ optional fused LayerNorm of the gated output) ----------------
// yx: [m][2048] = (ya | xb). grid MUST be MROWS blocks (1 row/block).
__global__ __launch_bounds__(256) void gru_combine(
  const unsigned short* __restrict__ rz,
  const unsigned short* __restrict__ yx,
  const float* __restrict__ xin, const float* __restrict__ bz,
  float* __restrict__ of, unsigned short* __restrict__ ob,
  const float* __restrict__ lng, const float* __restrict__ lnb,
  unsigned short* __restrict__ sn)
{
  int t = threadIdx.x;
  long row = blockIdx.x;
  long i = row*1024 + t*4;
  int col = t*4;
  us4 r4 = *(const us4*)(rz + row*2048 + col);
  us4 z4 = *(const us4*)(rz + row*2048 + 1024 + col);
  us4 a4 = *(const us4*)(yx + row*2048 + col);
  us4 b4 = *(const us4*)(yx + row*2048 + 1024 + col);
  f32x4 xv = *(const f32x4*)(xin + i);
  f32x4 bzv = *(const f32x4*)(bz + col);
  f32x4 o;
  #pragma unroll
  for (int jj=0;jj<4;jj++){
    float r = 1.f/(1.f + __expf(-b2f(r4[jj])));
    float z = 1.f/(1.f + __expf(-(b2f(z4[jj]) + bzv[jj] - 0.1f)));
    float h = tanhf(b2f(a4[jj]) + r*b2f(b4[jj]));
    o[jj] = (1.f - z)*xv[jj] + z*h;
  }
  *(f32x4*)(of+i) = o;
  if (ob){
    us4 q;
    #pragma unroll
    for (int jj=0;jj<4;jj++) q[jj] = f2b(o[jj]);
    *(us4*)(ob+i) = q;
  }
  if (sn){                                  // fused LN over this row's gated output
    float s = o[0]+o[1]+o[2]+o[3];
    float q = o[0]*o[0]+o[1]*o[1]+o[2]*o[2]+o[3]*o[3];
    #pragma unroll
    for (int off=32;off;off>>=1){ s += __shfl_xor(s,off); q += __shfl_xor(q,off); }
    __shared__ float rs[4], rq[4];
    int w = t >> 6;
    if ((t & 63) == 0){ rs[w]=s; rq[w]=q; }
    __syncthreads();
    s = rs[0]+rs[1]+rs[2]+rs[3];
    q = rq[0]+rq[1]+rq[2]+rq[3];
    float mean = s * (1.f/D_);
    float var  = q * (1.f/D_) - mean*mean;
    float rstd = rsqrtf(var + 1e-5f);
    f32x4 gv = ((const f32x4*)lng)[t];
    f32x4 bv = ((const f32x4*)lnb)[t];
    us4 oq;
    #pragma unroll
    for (int jj=0;jj<4;jj++) oq[jj] = f2b((o[jj]-mean)*rstd*gv[jj] + bv[jj]);
    *(us4*)(sn+i) = oq;
  }
}

// =======================================================================
extern "C" void kernel_launch(void* const* d_in, const int* in_sizes, int n_in,
                              void* d_out, int out_size, void* d_ws, size_t ws_size,
                              hipStream_t stream)
{
  const float* x    = (const float*)d_in[0];
  const float* Wq   = (const float*)d_in[1];
  const float* Wk   = (const float*)d_in[2];
  const float* Wv   = (const float*)d_in[3];
  const float* Wo   = (const float*)d_in[4];
  const float* ln1g = (const float*)d_in[5];
  const float* ln1b = (const float*)d_in[6];
  const float* W1   = (const float*)d_in[7];
  const float* b1   = (const float*)d_in[8];
  const float* W2   = (const float*)d_in[9];
  const float* b2   = (const float*)d_in[10];
  const float* ln2g = (const float*)d_in[11];
  const float* ln2b = (const float*)d_in[12];
  const float* g1W  = (const float*)d_in[13];
  const float* g1U  = (const float*)d_in[14];
  const float* g1bz = (const float*)d_in[15];
  const float* g2W  = (const float*)d_in[16];
  const float* g2U  = (const float*)d_in[17];
  const float* g2bz = (const float*)d_in[18];
  float* out = (float*)d_out;

  const size_t MB = 1u << 20;
  if (ws_size < 144*MB) return;
  char* base = (char*)d_ws;

  (void)hipFuncSetAttribute((const void*)gemm256<256>,
                            hipFuncAttributeMaxDynamicSharedMemorySize, 131072);
  (void)hipFuncSetAttribute((const void*)gemm256<128>,
                            hipFuncAttributeMaxDynamicSharedMemorySize, 98304);

  unsigned short* W    = (unsigned short*)(base);           // 16MB weight staging (phase-multiplexed)
  unsigned short* x_bf = (unsigned short*)(base + 16*MB);   // raw x bf16; dead after gate1 -> reused as sn
  unsigned short* sbf  = (unsigned short*)(base + 32*MB);   // src bf16 (gate1 out)
  unsigned short* src2 = (unsigned short*)(base + 48*MB);   // attn@Wo -> later ffb
  unsigned short* qkv  = (unsigned short*)(base + 64*MB);   // [8192][3072] 48MB
  unsigned short* vT   = (unsigned short*)(base + 112*MB);  // 16MB (dead after flash_attn)
  unsigned short* attn = (unsigned short*)(base + 128*MB);  // 16MB (also xn before QKV)
  unsigned short* xn   = attn;
  unsigned short* rz   = (unsigned short*)(base + 64*MB);   // [8192][2048] 32MB
  unsigned short* yx   = (unsigned short*)(base + 96*MB);   // [8192][2048] 32MB (ya|xb)
  unsigned short* sn   = x_bf;                              // LN2 output (x_bf dead by then)
  unsigned short* ff1  = (unsigned short*)(base + 80*MB);   // [8192][4096] 64MB (dead before gate2)
  unsigned short* ffb  = src2;

  const size_t E1M = 1048576;               // elements per 2MB
  unsigned short* BtRZ = W;                 // [2048][2048] 8MB (+ W2g/U2g at 4,5 E1M)
  unsigned short* W2g  = W + 4*E1M;
  unsigned short* U2g  = W + 5*E1M;
  unsigned short* W1T  = W;                 // FFN: [4096][1024] 8MB
  unsigned short* W2T  = W + 4*E1M;         // [1024][4096] 8MB
  unsigned short* Wqkv = W;                 // [3072][1024] 6MB
  unsigned short* WoT  = W + 3*E1M;

  const int NOSPLIT = 1 << 30;
  dim3 blk(256);
  auto G2 = [&](const unsigned short* A1, const unsigned short* A2, int K1, long lda,
                const unsigned short* Bt, long ldb, unsigned short* C, long ldc,
                const float* bias, int M, int N, int K, int flags,
                const unsigned short* A1b, const unsigned short* Btb, int N1){
    gemm256<256><<<dim3(N/256, M/256), dim3(512), 131072, stream>>>(
        A1,A2,K1,lda,Bt,ldb,C,ldc,bias,K,flags,A1b,Btb,N1);
  };
  auto G2n = [&](const unsigned short* A1, const unsigned short* A2, int K1, long lda,
                 const unsigned short* Bt, long ldb, unsigned short* C, long ldc,
                 const float* bias, int M, int N, int K, int flags){
    gemm256<128><<<dim3(N/128, M/256), dim3(512), 98304, stream>>>(
        A1,A2,K1,lda,Bt,ldb,C,ldc,bias,K,flags,A1,Bt,NOSPLIT);
  };

  // ---- phase 0: attention weights + fused LN1/cast ----
  tr_f2b<<<dim3(32,32), blk, 0, stream>>>(Wq, Wqkv,          D_, D_);
  tr_f2b<<<dim3(32,32), blk, 0, stream>>>(Wk, Wqkv + 1*E1M,  D_, D_);
  tr_f2b<<<dim3(32,32), blk, 0, stream>>>(Wv, Wqkv + 2*E1M,  D_, D_);
  tr_f2b<<<dim3(32,32), blk, 0, stream>>>(Wo, WoT,           D_, D_);
  ln_cast<<<dim3(MROWS), blk, 0, stream>>>(x, ln1g, ln1b, xn, x_bf);

  // ---- phase 1: QKV (split: QK as one full 256-block BN=256 round, V as a 256-block BN=128 round)
  G2(xn, xn, D_, D_, Wqkv, D_, qkv, 3072, nullptr, MROWS, 2048, D_, 0, xn, Wqkv, NOSPLIT);
  G2n(xn, xn, D_, D_, Wqkv + 2*E1M, D_, qkv + 2048, 3072, nullptr, MROWS, 1024, D_, 0);
  build_vT<<<dim3(32,2,128), blk, 0, stream>>>(qkv + 2048, vT);
  flash_attn<<<dim3(4, B_*H_), blk, 0, stream>>>(qkv, vT, attn);
  G2n(attn, attn, D_, D_, WoT, D_, src2, D_, nullptr, MROWS, D_, D_, 0);

  // ---- phase 2: GRU gate 1 (x-path = x_bf, y-path = src2), LN2 fused into combine ----
  tr_gate<<<dim3(32,32,6), blk, 0, stream>>>(g1W, g1U, W);
  G2(src2, x_bf, D_, D_, BtRZ, 2048, rz, 2048, nullptr, MROWS, 2048, 2048, 0, src2, BtRZ, NOSPLIT);
  G2(src2, src2, D_, D_, W2g, D_, yx, 2048, nullptr, MROWS, 2048, D_, 0, x_bf, U2g, 1024);
  gru_combine<<<dim3(MROWS), blk, 0, stream>>>(rz, yx, x, g1bz, out, sbf, ln2g, ln2b, sn);

  // ---- phase 3: FFN ----
  tr_f2b<<<dim3(32,128), blk, 0, stream>>>(W1, W1T, FF_, D_);
  tr_f2b<<<dim3(128,32), blk, 0, stream>>>(W2, W2T, D_, FF_);
  G2(sn, sn, D_, D_, W1T, D_, ff1, FF_, b1, MROWS, FF_, D_, FRELU, sn, W1T, NOSPLIT);
  G2n(ff1, ff1, FF_, FF_, W2T, FF_, ffb, D_, b2, MROWS, D_, FF_, 0);

  // ---- phase 4: GRU gate 2 (x-path = sbf, y-path = ffb) ----
  tr_gate<<<dim3(32,32,6), blk, 0, stream>>>(g2W, g2U, W);
  G2(ffb, sbf, D_, D_, BtRZ, 2048, rz, 2048, nullptr, MROWS, 2048, 2048, 0, ffb, BtRZ, NOSPLIT);
  G2(ffb, ffb, D_, D_, W2g, D_, yx, 2048, nullptr, MROWS, 2048, D_, 0, sbf, U2g, 1024);
  gru_combine<<<dim3(MROWS), blk, 0, stream>>>(rz, yx, out, g2bz, out, nullptr, nullptr, nullptr, nullptr);
}